// Round 6
// baseline (132.340 us; speedup 1.0000x reference)
//
#include <hip/hip_runtime.h>

#define NFULL 128
#define NOUT  122
#define NBLK  1024

// Per-wave private LDS: ws[5][14][18] W-sums (1260 fl) then hs[5][8][18] H-sums (720 fl)
#define WS_R 18
#define WS_Q 252          // 14*18
#define HS_R 18
#define HS_Q 144          // 8*18
#define HS_OFF 1260
#define WAVE_LDS 1984     // padded per-wave stride (7936 B)

__device__ __forceinline__ void wsum_task(const float* __restrict__ px,
                                          const float* __restrict__ py,
                                          float* __restrict__ wsp)
{
    float xs[8], ys[8];
#pragma unroll
    for (int k = 0; k < 4; ++k) {
        float2 tx = *(const float2*)(px + 2 * k);
        float2 ty = *(const float2*)(py + 2 * k);
        xs[2 * k] = tx.x; xs[2 * k + 1] = tx.y;
        ys[2 * k] = ty.x; ys[2 * k + 1] = ty.y;
    }
    float sx = 0.f, sy = 0.f, sxx = 0.f, syy = 0.f, sxy = 0.f;
#pragma unroll
    for (int k = 0; k < 7; ++k) {
        sx += xs[k]; sy += ys[k];
        sxx = fmaf(xs[k], xs[k], sxx);
        syy = fmaf(ys[k], ys[k], syy);
        sxy = fmaf(xs[k], ys[k], sxy);
    }
    float tx2 = sx - xs[0] + xs[7];
    float ty2 = sy - ys[0] + ys[7];
    float txx = sxx - xs[0] * xs[0] + xs[7] * xs[7];
    float tyy = syy - ys[0] * ys[0] + ys[7] * ys[7];
    float txy = sxy - xs[0] * ys[0] + xs[7] * ys[7];
    *(float2*)(wsp + 0 * WS_Q) = make_float2(sx,  tx2);
    *(float2*)(wsp + 1 * WS_Q) = make_float2(sy,  ty2);
    *(float2*)(wsp + 2 * WS_Q) = make_float2(sxx, txx);
    *(float2*)(wsp + 3 * WS_Q) = make_float2(syy, tyy);
    *(float2*)(wsp + 4 * WS_Q) = make_float2(sxy, txy);
}

__global__ __launch_bounds__(256, 4)
void ssim3d_kernel(const float* __restrict__ X, const float* __restrict__ Y,
                   const float* __restrict__ DR, double* __restrict__ wsout, int mode)
{
    __shared__ __align__(16) float lds[4 * WAVE_LDS];   // 31744 B

    const int tid  = threadIdx.x;
    const int wave = tid >> 6;
    const int lane = tid & 63;
    const int c = lane & 7;        // colpair 0..7
    const int g = lane >> 3;       // row-in-tile 0..7

    int bi = blockIdx.x;
    const int bb = bi & 3;  bi >>= 2;   // batch
    const int ht = bi & 3;  bi >>= 2;   // 4 h-tiles of 32
    const int wt = bi & 7;  bi >>= 3;   // 8 w-tiles of 16
    const int dc = bi;                  // 8 d-chunks

    const int hbase = ht * 32 + wave * 8;   // wave's first output row
    const int w0 = wt * 16;
    const int csize = (dc < 2) ? 16 : 15;
    const int d0 = (dc < 2) ? (dc << 4) : (32 + (dc - 2) * 15);
    const int nsl = csize + 6;              // slices d0..d0+nsl-1 (<=127)

    // SSIM constants scaled by 343^2 (ratio-invariant; validated R4/R5)
    const float dr  = DR[bb];
    const float c1s = (0.01f * dr) * (0.01f * dr) * 117649.0f;
    const float c2s = (0.03f * dr) * (0.03f * dr) * 117649.0f;
    const float tni = 1.0f / 343.0f;
    const float kkA = 2.0f * 117649.0f / 342.0f;
    const float kkB = 117649.0f / 342.0f;

    float* wsb = lds + wave * WAVE_LDS;
    float* hsb = wsb + HS_OFF;

    // ---- phase A addressing (2 tasks/lane: rows g and g+8 of 14) ----
    int grow0 = hbase + g;      if (grow0 > NFULL - 1) grow0 = NFULL - 1;
    int grow1 = hbase + g + 8;  if (grow1 > NFULL - 1) grow1 = NFULL - 1;
    const bool hasA1 = (g < 6);
    int colb = w0 + 2 * c; if (colb > NFULL - 8) colb = NFULL - 8;  // stay in-row
    float* wsp0 = wsb + g * WS_R + 2 * c;
    float* wsp1 = wsb + (g + 8) * WS_R + 2 * c;

    // ---- phase B addressing (40 active lanes: c_b 0..7 x q_b 0..4) ----
    const bool actB = (lane < 40);
    const int cB = lane & 7;
    const int qB = lane >> 3;
    const float* srcB = wsb + qB * WS_Q + 2 * cB;
    float*       dstB = hsb + qB * HS_Q + 2 * cB;

    // ---- phase C addressing / masks ----
    const float* srcC = hsb + g * HS_R + 2 * c;
    const int gh  = hbase + g;
    const int gw0 = w0 + 2 * c;
    const bool vh   = (gh < NOUT);
    const bool vld0 = vh && (gw0 < NOUT);
    const bool vld1 = vh && (gw0 + 1 < NOUT);

    const size_t planeStride = (size_t)NFULL * NFULL;
    const size_t bbase = (size_t)bb * NFULL * planeStride;

    float2 ring[7][5];
    float2 run[5];
#pragma unroll
    for (int k = 0; k < 7; ++k)
#pragma unroll
        for (int q = 0; q < 5; ++q) ring[k][q] = make_float2(0.f, 0.f);
#pragma unroll
    for (int q = 0; q < 5; ++q) run[q] = make_float2(0.f, 0.f);
    float acc = 0.0f;

    // Wave-autonomous main loop: NO barriers. A->B->C chained via lgkmcnt only.
    for (int base = 0; base < nsl; base += 7) {
#pragma unroll
        for (int u = 0; u < 7; ++u) {
            const int s = base + u;
            if (s < nsl) {
                const int dIn = d0 + s;
                const float* Xp = X + bbase + (size_t)dIn * planeStride;
                const float* Yp = Y + bbase + (size_t)dIn * planeStride;

                // ---- A: W-sums for 14 rows (2 tasks/lane) -> ws ----
                wsum_task(Xp + grow0 * NFULL + colb, Yp + grow0 * NFULL + colb, wsp0);
                if (hasA1)
                    wsum_task(Xp + grow1 * NFULL + colb, Yp + grow1 * NFULL + colb, wsp1);

                // ---- B: rolling H-sums, 14 rows -> 8 rows (40 lanes) ----
                if (actB) {
                    float2 v[14];
#pragma unroll
                    for (int r = 0; r < 14; ++r)
                        v[r] = *(const float2*)(srcB + r * WS_R);
                    float ax = v[0].x, ay = v[0].y;
#pragma unroll
                    for (int r = 1; r < 7; ++r) { ax += v[r].x; ay += v[r].y; }
                    *(float2*)(dstB + 0 * HS_R) = make_float2(ax, ay);
#pragma unroll
                    for (int i = 1; i < 8; ++i) {
                        ax += v[6 + i].x - v[i - 1].x;
                        ay += v[6 + i].y - v[i - 1].y;
                        *(float2*)(dstB + i * HS_R) = make_float2(ax, ay);
                    }
                }

                // ---- C: D-ring + SSIM ----
                {
                    const int slot = u;    // s % 7, static after unroll
                    float2 p[5];
#pragma unroll
                    for (int q = 0; q < 5; ++q)
                        p[q] = *(const float2*)(srcC + q * HS_Q);
#pragma unroll
                    for (int q = 0; q < 5; ++q) {
                        run[q].x += p[q].x - ring[slot][q].x;
                        run[q].y += p[q].y - ring[slot][q].y;
                        ring[slot][q] = p[q];
                    }
                    if (s >= 6) {
#pragma unroll
                        for (int j = 0; j < 2; ++j) {
                            const bool vld = j ? vld1 : vld0;
                            if (vld) {
                                float Sx  = j ? run[0].y : run[0].x;
                                float Sy  = j ? run[1].y : run[1].x;
                                float Sxx = j ? run[2].y : run[2].x;
                                float Syy = j ? run[3].y : run[3].x;
                                float Sxy = j ? run[4].y : run[4].x;
                                float P = Sx * Sy;
                                float Q = fmaf(Sx, Sx, Sy * Sy);
                                float A1 = fmaf(2.f, P, c1s);
                                float A2 = fmaf(kkA, fmaf(-tni, P, Sxy), c2s);
                                float B1 = Q + c1s;
                                float B2 = fmaf(kkB, fmaf(-tni, Q, Sxx + Syy), c2s);
                                float num = A1 * A2;
                                float den = B1 * B2;
                                float r0 = __builtin_amdgcn_rcpf(den);
                                r0 = r0 * fmaf(-den, r0, 2.0f);   // 1 Newton step
                                acc = fmaf(num, r0, acc);
                            }
                        }
                    }
                }
            }
        }
    }

    // ---- reduction: wave shuffle -> LDS -> per-block partial (double) ----
#pragma unroll
    for (int off = 32; off; off >>= 1) acc += __shfl_down(acc, off);
    __syncthreads();                       // safe: main loop done
    if (lane == 0) lds[wave] = acc;
    __syncthreads();
    if (tid == 0) {
        double t = (double)lds[0] + (double)lds[1] + (double)lds[2] + (double)lds[3];
        if (mode) wsout[blockIdx.x] = t;
        else      atomicAdd(wsout, t);
    }
}

__global__ void ssim3d_finalize(const double* __restrict__ ws, float* __restrict__ out, int mode)
{
    if (mode) {
        __shared__ double sm[4];
        const int tid = threadIdx.x;
        double t = 0.0;
        for (int i = tid; i < NBLK; i += 256) t += ws[i];
#pragma unroll
        for (int off = 32; off; off >>= 1) t += __shfl_down(t, off);
        if ((tid & 63) == 0) sm[tid >> 6] = t;
        __syncthreads();
        if (tid == 0) {
            double r = sm[0] + sm[1] + sm[2] + sm[3];
            out[0] = (float)(r * (1.0 / 7263392.0));   // 4 * 122^3
        }
    } else {
        if (threadIdx.x == 0)
            out[0] = (float)(ws[0] * (1.0 / 7263392.0));
    }
}

extern "C" void kernel_launch(void* const* d_in, const int* in_sizes, int n_in,
                              void* d_out, int out_size, void* d_ws, size_t ws_size,
                              hipStream_t stream)
{
    const float* X  = (const float*)d_in[0];
    const float* Y  = (const float*)d_in[1];
    const float* DR = (const float*)d_in[2];
    double* ws = (double*)d_ws;

    const int mode = (ws_size >= NBLK * sizeof(double)) ? 1 : 0;
    if (!mode) hipMemsetAsync(d_ws, 0, sizeof(double), stream);
    ssim3d_kernel<<<NBLK, 256, 0, stream>>>(X, Y, DR, ws, mode);
    ssim3d_finalize<<<1, 256, 0, stream>>>(ws, (float*)d_out, mode);
}

// Round 7
// 129.270 us; speedup vs baseline: 1.0237x; 1.0237x over previous
//
#include <hip/hip_runtime.h>

#define NFULL 128
#define NOUT  122
#define NBLK  1024

// Per-wave private LDS, lane-linear layouts (bank-conflict-free A/C):
// ws[q][r 0..13][c 0..7] float2 at q*WS_Q + (r*8+c)*2 ; WS_Q=232 (mod 32 = 8)
// hs[q][g 0..7][c 0..7]  float2 at q*HS_Q + (g*8+c)*2 ; HS_Q=136 (mod 32 = 8)
#define WS_Q 232
#define WS_R 16
#define HS_Q 136
#define HS_R 16
#define HS_OFF 1160        // 5*232
#define WAVE_LDS 1856      // per-wave float stride (7424 B); 4 waves = 29696 B

__device__ __forceinline__ void wsum_task(const float* __restrict__ px,
                                          const float* __restrict__ py,
                                          float* __restrict__ wsp)
{
    float xs[8], ys[8];
#pragma unroll
    for (int k = 0; k < 4; ++k) {
        float2 tx = *(const float2*)(px + 2 * k);
        float2 ty = *(const float2*)(py + 2 * k);
        xs[2 * k] = tx.x; xs[2 * k + 1] = tx.y;
        ys[2 * k] = ty.x; ys[2 * k + 1] = ty.y;
    }
    float sx = 0.f, sy = 0.f, sxx = 0.f, syy = 0.f, sxy = 0.f;
#pragma unroll
    for (int k = 0; k < 7; ++k) {
        sx += xs[k]; sy += ys[k];
        sxx = fmaf(xs[k], xs[k], sxx);
        syy = fmaf(ys[k], ys[k], syy);
        sxy = fmaf(xs[k], ys[k], sxy);
    }
    float tx2 = sx - xs[0] + xs[7];
    float ty2 = sy - ys[0] + ys[7];
    float txx = sxx - xs[0] * xs[0] + xs[7] * xs[7];
    float tyy = syy - ys[0] * ys[0] + ys[7] * ys[7];
    float txy = sxy - xs[0] * ys[0] + xs[7] * ys[7];
    *(float2*)(wsp + 0 * WS_Q) = make_float2(sx,  tx2);
    *(float2*)(wsp + 1 * WS_Q) = make_float2(sy,  ty2);
    *(float2*)(wsp + 2 * WS_Q) = make_float2(sxx, txx);
    *(float2*)(wsp + 3 * WS_Q) = make_float2(syy, tyy);
    *(float2*)(wsp + 4 * WS_Q) = make_float2(sxy, txy);
}

__global__ __launch_bounds__(256, 4)
void ssim3d_kernel(const float* __restrict__ X, const float* __restrict__ Y,
                   const float* __restrict__ DR, double* __restrict__ wsout, int mode)
{
    __shared__ __align__(16) float lds[4 * WAVE_LDS];   // 29696 B

    const int tid  = threadIdx.x;
    const int wave = tid >> 6;
    const int lane = tid & 63;
    const int c = lane & 7;        // colpair 0..7
    const int g = lane >> 3;       // row-in-tile 0..7

    int bi = blockIdx.x;
    const int bb = bi & 3;  bi >>= 2;   // batch
    const int ht = bi & 3;  bi >>= 2;   // 4 h-tiles of 32
    const int wt = bi & 7;  bi >>= 3;   // 8 w-tiles of 16
    const int dc = bi;                  // 8 d-chunks

    const int hbase = ht * 32 + wave * 8;   // wave's first output row
    const int w0 = wt * 16;
    const int csize = (dc < 2) ? 16 : 15;
    const int d0 = (dc < 2) ? (dc << 4) : (32 + (dc - 2) * 15);
    const int nsl = csize + 6;              // slices d0..d0+nsl-1 (<=127)

    // SSIM constants scaled by 343^2 (ratio-invariant; validated R4-R6)
    const float dr  = DR[bb];
    const float c1s = (0.01f * dr) * (0.01f * dr) * 117649.0f;
    const float c2s = (0.03f * dr) * (0.03f * dr) * 117649.0f;
    const float tni = 1.0f / 343.0f;
    const float kkA = 2.0f * 117649.0f / 342.0f;
    const float kkB = 117649.0f / 342.0f;

    float* wsb = lds + wave * WAVE_LDS;
    float* hsb = wsb + HS_OFF;

    // ---- phase A addressing (2 tasks/lane: rows g and g+8 of 14) ----
    int grow0 = hbase + g;      if (grow0 > NFULL - 1) grow0 = NFULL - 1;
    int grow1 = hbase + g + 8;  if (grow1 > NFULL - 1) grow1 = NFULL - 1;
    const bool hasA1 = (g < 6);
    int colb = w0 + 2 * c; if (colb > NFULL - 8) colb = NFULL - 8;  // stay in-row
    float* wsp0 = wsb + lane * 2;          // task t=lane    -> contiguous
    float* wsp1 = wsb + 128 + lane * 2;    // task t=64+lane -> contiguous

    // ---- phase B addressing (40 active lanes: q 0..4 x c 0..7) ----
    const bool actB = (lane < 40);
    const int cB = lane & 7;
    const int qB = lane >> 3;
    const float* srcB = wsb + qB * WS_Q + 2 * cB;
    float*       dstB = hsb + qB * HS_Q + 2 * cB;

    // ---- phase C addressing / masks (contiguous per instruction) ----
    const float* srcC = hsb + lane * 2;
    const int gh  = hbase + g;
    const int gw0 = w0 + 2 * c;
    const bool vh   = (gh < NOUT);
    const bool vld0 = vh && (gw0 < NOUT);
    const bool vld1 = vh && (gw0 + 1 < NOUT);

    const size_t planeStride = (size_t)NFULL * NFULL;
    const size_t bbase = (size_t)bb * NFULL * planeStride;

    float2 ring[7][5];
    float2 run[5];
#pragma unroll
    for (int k = 0; k < 7; ++k)
#pragma unroll
        for (int q = 0; q < 5; ++q) ring[k][q] = make_float2(0.f, 0.f);
#pragma unroll
    for (int q = 0; q < 5; ++q) run[q] = make_float2(0.f, 0.f);
    float acc = 0.0f;

    // Wave-autonomous main loop: NO barriers. A->B->C chained via lgkmcnt only.
    for (int base = 0; base < nsl; base += 7) {
#pragma unroll
        for (int u = 0; u < 7; ++u) {
            const int s = base + u;
            if (s < nsl) {
                const int dIn = d0 + s;
                const float* Xp = X + bbase + (size_t)dIn * planeStride;
                const float* Yp = Y + bbase + (size_t)dIn * planeStride;

                // ---- A: W-sums for 14 rows (2 tasks/lane) -> ws ----
                wsum_task(Xp + grow0 * NFULL + colb, Yp + grow0 * NFULL + colb, wsp0);
                if (hasA1)
                    wsum_task(Xp + grow1 * NFULL + colb, Yp + grow1 * NFULL + colb, wsp1);

                // ---- B: rolling H-sums, 14 rows -> 8 rows (40 lanes) ----
                if (actB) {
                    float2 v[14];
#pragma unroll
                    for (int r = 0; r < 14; ++r)
                        v[r] = *(const float2*)(srcB + r * WS_R);
                    float ax = v[0].x, ay = v[0].y;
#pragma unroll
                    for (int r = 1; r < 7; ++r) { ax += v[r].x; ay += v[r].y; }
                    *(float2*)(dstB + 0 * HS_R) = make_float2(ax, ay);
#pragma unroll
                    for (int i = 1; i < 8; ++i) {
                        ax += v[6 + i].x - v[i - 1].x;
                        ay += v[6 + i].y - v[i - 1].y;
                        *(float2*)(dstB + i * HS_R) = make_float2(ax, ay);
                    }
                }

                // ---- C: D-ring + SSIM ----
                {
                    const int slot = u;    // s % 7, static after unroll
                    float2 p[5];
#pragma unroll
                    for (int q = 0; q < 5; ++q)
                        p[q] = *(const float2*)(srcC + q * HS_Q);
#pragma unroll
                    for (int q = 0; q < 5; ++q) {
                        run[q].x += p[q].x - ring[slot][q].x;
                        run[q].y += p[q].y - ring[slot][q].y;
                        ring[slot][q] = p[q];
                    }
                    if (s >= 6) {
#pragma unroll
                        for (int j = 0; j < 2; ++j) {
                            const bool vld = j ? vld1 : vld0;
                            if (vld) {
                                float Sx  = j ? run[0].y : run[0].x;
                                float Sy  = j ? run[1].y : run[1].x;
                                float Sxx = j ? run[2].y : run[2].x;
                                float Syy = j ? run[3].y : run[3].x;
                                float Sxy = j ? run[4].y : run[4].x;
                                float P = Sx * Sy;
                                float Q = fmaf(Sx, Sx, Sy * Sy);
                                float A1 = fmaf(2.f, P, c1s);
                                float A2 = fmaf(kkA, fmaf(-tni, P, Sxy), c2s);
                                float B1 = Q + c1s;
                                float B2 = fmaf(kkB, fmaf(-tni, Q, Sxx + Syy), c2s);
                                float num = A1 * A2;
                                float den = B1 * B2;
                                float r0 = __builtin_amdgcn_rcpf(den);
                                r0 = r0 * fmaf(-den, r0, 2.0f);   // 1 Newton step
                                acc = fmaf(num, r0, acc);
                            }
                        }
                    }
                }
            }
        }
    }

    // ---- reduction: wave shuffle -> LDS -> per-block partial (double) ----
#pragma unroll
    for (int off = 32; off; off >>= 1) acc += __shfl_down(acc, off);
    __syncthreads();                       // safe: main loop done
    if (lane == 0) lds[wave] = acc;
    __syncthreads();
    if (tid == 0) {
        double t = (double)lds[0] + (double)lds[1] + (double)lds[2] + (double)lds[3];
        if (mode) wsout[blockIdx.x] = t;
        else      atomicAdd(wsout, t);
    }
}

__global__ void ssim3d_finalize(const double* __restrict__ ws, float* __restrict__ out, int mode)
{
    if (mode) {
        __shared__ double sm[4];
        const int tid = threadIdx.x;
        double t = 0.0;
        for (int i = tid; i < NBLK; i += 256) t += ws[i];
#pragma unroll
        for (int off = 32; off; off >>= 1) t += __shfl_down(t, off);
        if ((tid & 63) == 0) sm[tid >> 6] = t;
        __syncthreads();
        if (tid == 0) {
            double r = sm[0] + sm[1] + sm[2] + sm[3];
            out[0] = (float)(r * (1.0 / 7263392.0));   // 4 * 122^3
        }
    } else {
        if (threadIdx.x == 0)
            out[0] = (float)(ws[0] * (1.0 / 7263392.0));
    }
}

extern "C" void kernel_launch(void* const* d_in, const int* in_sizes, int n_in,
                              void* d_out, int out_size, void* d_ws, size_t ws_size,
                              hipStream_t stream)
{
    const float* X  = (const float*)d_in[0];
    const float* Y  = (const float*)d_in[1];
    const float* DR = (const float*)d_in[2];
    double* ws = (double*)d_ws;

    const int mode = (ws_size >= NBLK * sizeof(double)) ? 1 : 0;
    if (!mode) hipMemsetAsync(d_ws, 0, sizeof(double), stream);
    ssim3d_kernel<<<NBLK, 256, 0, stream>>>(X, Y, DR, ws, mode);
    ssim3d_finalize<<<1, 256, 0, stream>>>(ws, (float*)d_out, mode);
}